// Round 5
// baseline (1747.130 us; speedup 1.0000x reference)
//
#include <hip/hip_runtime.h>
#include <hip/hip_bf16.h>

typedef __bf16 bf16_t;
typedef __bf16 bf16x8 __attribute__((ext_vector_type(8)));
typedef float f32x4 __attribute__((ext_vector_type(4)));
typedef unsigned int u32;

constexpr int NODEMB = 128;
constexpr int HIDDEN = 128;
constexpr int EDGEMB = 128;
constexpr int NEDGES = 800000;
constexpr int NNODES = 50000;

constexpr int W1S = 296;   // padded K stride (elements) for W1T (16B-aligned rows)
constexpr int W2S = 136;   // padded K stride for W2T
constexpr int W1_ELEMS = HIDDEN * W1S;   // 37888
constexpr int W2_ELEMS = EDGEMB * W2S;   // 17408
constexpr int TILE_EDGES = 256;          // 16 waves x 16 edges
constexpr int NTILES = NEDGES / TILE_EDGES;  // 3125 exactly

// ---------------------------------------------------------------------------
// Module-global tables: allocated at .so load (graph-capture safe), rebuilt
// from restored inputs by prep kernels on EVERY launch.
// ---------------------------------------------------------------------------
__device__ __align__(16) bf16_t   g_w1t[W1_ELEMS];
__device__ __align__(16) bf16_t   g_w2t[W2_ELEMS];
__device__ __align__(16) bf16_t   g_nh[(size_t)NNODES * NODEMB];  // 12.8 MB
__device__ __align__(16) unsigned g_nf[NNODES];                   // packed 2x bf16
__device__ __align__(16) bf16_t   g_dist[NEDGES];

__device__ __forceinline__ bf16x8 cvt8(f32x4 lo, f32x4 hi) {
    bf16x8 t;
    t[0] = (bf16_t)lo[0]; t[1] = (bf16_t)lo[1]; t[2] = (bf16_t)lo[2]; t[3] = (bf16_t)lo[3];
    t[4] = (bf16_t)hi[0]; t[5] = (bf16_t)hi[1]; t[6] = (bf16_t)hi[2]; t[7] = (bf16_t)hi[3];
    return t;
}

// ---------------------------------------------------------------------------
// Prep 1: K-permuted, zero-padded, K-major bf16 weights.
// K-order: [0,128)=dst_hidden (orig rows 2..129), [128,256)=src_hidden
// (orig 132..259), 256=row0, 257=row1, 258=row130, 259=row131, 260=row260,
// 261=BIAS ROW (b1; X[261]==1.0), [262,296)=zero.
// ---------------------------------------------------------------------------
__global__ void prep_weights(const float* __restrict__ W1, const float* __restrict__ b1,
                             const float* __restrict__ W2) {
    int i = blockIdx.x * blockDim.x + threadIdx.x;
    if (i < W1_ELEMS) {
        int n = i / W1S, k = i - n * W1S;
        float v = 0.f;
        if (k < 128)       v = W1[(2 + k) * HIDDEN + n];
        else if (k < 256)  v = W1[(132 + (k - 128)) * HIDDEN + n];
        else if (k == 256) v = W1[0 * HIDDEN + n];
        else if (k == 257) v = W1[1 * HIDDEN + n];
        else if (k == 258) v = W1[130 * HIDDEN + n];
        else if (k == 259) v = W1[131 * HIDDEN + n];
        else if (k == 260) v = W1[260 * HIDDEN + n];
        else if (k == 261) v = b1[n];
        g_w1t[n * W1S + k] = (bf16_t)v;
    } else if (i < W1_ELEMS + W2_ELEMS) {
        int j = i - W1_ELEMS;
        int n = j / W2S, k = j - n * W2S;
        float v = (k < 128) ? W2[k * EDGEMB + n] : 0.f;
        g_w2t[n * W2S + k] = (bf16_t)v;
    }
}

// ---------------------------------------------------------------------------
// Prep 2: bf16 gather tables (same rounding as in-kernel cast).
// ---------------------------------------------------------------------------
__global__ void prep_nodes(const float* __restrict__ nh, const float* __restrict__ nf,
                           const float* __restrict__ dist) {
    int i = blockIdx.x * blockDim.x + threadIdx.x;
    constexpr int NH_CHUNKS = NNODES * NODEMB / 8;  // 800000
    if (i < NH_CHUNKS) {
        const f32x4* p = (const f32x4*)nh;
        ((bf16x8*)g_nh)[i] = cvt8(p[2 * i], p[2 * i + 1]);
    }
    if (i < NEDGES) g_dist[i] = (bf16_t)dist[i];
    if (i < NNODES) {
        union { unsigned u; bf16_t h[2]; } c;
        c.h[0] = (bf16_t)nf[2 * i];
        c.h[1] = (bf16_t)nf[2 * i + 1];
        g_nf[i] = c.u;
    }
}

// ---------------------------------------------------------------------------
// Main: 1024 threads = 16 waves/block, 1 block/CU (111 KB LDS) = 4 waves/SIMD.
// Operand-swapped MFMAs: D = mfma(W_frag, X_frag) gives transposed outputs, so
// (a) layer1->layer2 handoff is an in-register 4-lane shuffle (no LDS, no
//     barriers in the main loop),
// (b) output stores are f32x4 (64B segments).
// b1 folded into W1 K-row 261; b2 via 512B LDS.
// ---------------------------------------------------------------------------
__global__ __launch_bounds__(1024, 4) void edge_mlp(
    const int* __restrict__ src_idx,
    const int* __restrict__ dst_idx,
    const float* __restrict__ b2,
    float* __restrict__ out)
{
    __shared__ bf16_t sW[W1_ELEMS + W2_ELEMS];   // 110,592 B
    __shared__ float  sB2[EDGEMB];               //     512 B

    const int tid = threadIdx.x;

    {   // stage weights into LDS, 16B chunks
        const uint4* g1 = (const uint4*)g_w1t;
        const uint4* g2 = (const uint4*)g_w2t;
        uint4* l1 = (uint4*)sW;
        uint4* l2 = (uint4*)(sW + W1_ELEMS);
        for (int i = tid; i < W1_ELEMS / 8; i += 1024) l1[i] = g1[i];
        for (int i = tid; i < W2_ELEMS / 8; i += 1024) l2[i] = g2[i];
        if (tid < EDGEMB) sB2[tid] = b2[tid];
    }
    __syncthreads();
    const bf16_t* sW1 = sW;
    const bf16_t* sW2 = sW + W1_ELEMS;

    const int wid  = tid >> 6;
    const int lane = tid & 63;
    const int r    = lane & 15;          // edge-in-wave / W row-in-16
    const int g    = lane >> 4;          // k-chunk selector
    const int srcA = r + 32 * (g & 1);   // shuffle source lane, g_s = 2*(g&1)
    const int srcB = srcA + 16;          // g_s = 2*(g&1)+1
    const bool hi  = (g >> 1) != 0;      // selects nt_s = 2*ks2+1 variant

    for (int tile = blockIdx.x; tile < NTILES; tile += (int)gridDim.x) {
        const int e  = tile * TILE_EDGES + wid * 16 + r;
        const int di = dst_idx[e];
        const int si = src_idx[e];

        // ---- gather X fragments (B-operand): lane (r,g) = edge r, chunk g*8 ----
        bf16x8 a[9];
        const bf16x8* dp = (const bf16x8*)(g_nh + (size_t)di * NODEMB);
        const bf16x8* sp = (const bf16x8*)(g_nh + (size_t)si * NODEMB);
        #pragma unroll
        for (int ks = 0; ks < 4; ++ks) a[ks] = dp[ks * 4 + g];
        #pragma unroll
        for (int ks = 0; ks < 4; ++ks) a[4 + ks] = sp[ks * 4 + g];
        {
            bf16x8 t;
            #pragma unroll
            for (int j = 0; j < 8; ++j) t[j] = (bf16_t)0.f;
            if (g == 0) {   // k=256..263; k>=264 lanes stay zero (weights there are 0)
                union { unsigned u; bf16_t h[2]; } c1, c2;
                c1.u = g_nf[di]; c2.u = g_nf[si];
                t[0] = c1.h[0]; t[1] = c1.h[1];
                t[2] = c2.h[0]; t[3] = c2.h[1];
                t[4] = g_dist[e];
                t[5] = (bf16_t)1.f;   // k=261: multiplies the b1 row of W1T
            }
            a[8] = t;
        }

        // ---- layer 1 (swapped): lane holds h[edge r][n = nt*16 + g*4 + ii] ----
        f32x4 acc[8];
        #pragma unroll
        for (int nt = 0; nt < 8; ++nt) { acc[nt][0]=0.f; acc[nt][1]=0.f; acc[nt][2]=0.f; acc[nt][3]=0.f; }
        #pragma unroll
        for (int ks = 0; ks < 9; ++ks) {
            #pragma unroll
            for (int nt = 0; nt < 8; ++nt) {
                bf16x8 w = *(const bf16x8*)&sW1[(nt * 16 + r) * W1S + ks * 32 + g * 8];
                acc[nt] = __builtin_amdgcn_mfma_f32_16x16x32_bf16(w, a[ks], acc[nt], 0, 0, 0);
            }
        }

        // ---- relu + pack to bf16 pairs ----
        u32 p0[8], p1[8];
        #pragma unroll
        for (int nt = 0; nt < 8; ++nt) {
            union { u32 u; bf16_t h[2]; } c0, c1;
            float v0 = acc[nt][0] > 0.f ? acc[nt][0] : 0.f;
            float v1 = acc[nt][1] > 0.f ? acc[nt][1] : 0.f;
            float v2 = acc[nt][2] > 0.f ? acc[nt][2] : 0.f;
            float v3 = acc[nt][3] > 0.f ? acc[nt][3] : 0.f;
            c0.h[0] = (bf16_t)v0; c0.h[1] = (bf16_t)v1;
            c1.h[0] = (bf16_t)v2; c1.h[1] = (bf16_t)v3;
            p0[nt] = c0.u; p1[nt] = c1.u;
        }

        // ---- in-register transpose among lanes {r, r+16, r+32, r+48} ----
        // target lane (r,g), frag ks2 = h[edge r][ks2*32 + g*8 .. +8)
        bf16x8 hb[4];
        #pragma unroll
        for (int ks2 = 0; ks2 < 4; ++ks2) {
            u32 a0 = __shfl(p0[2 * ks2],     srcA, 64);
            u32 b0 = __shfl(p0[2 * ks2 + 1], srcA, 64);
            u32 a1 = __shfl(p1[2 * ks2],     srcA, 64);
            u32 b1v = __shfl(p1[2 * ks2 + 1], srcA, 64);
            u32 a2 = __shfl(p0[2 * ks2],     srcB, 64);
            u32 b2v = __shfl(p0[2 * ks2 + 1], srcB, 64);
            u32 a3 = __shfl(p1[2 * ks2],     srcB, 64);
            u32 b3v = __shfl(p1[2 * ks2 + 1], srcB, 64);
            union { u32 u[4]; bf16x8 v; } m;
            m.u[0] = hi ? b0  : a0;
            m.u[1] = hi ? b1v : a1;
            m.u[2] = hi ? b2v : a2;
            m.u[3] = hi ? b3v : a3;
            hb[ks2] = m.v;
        }

        // ---- layer 2 (swapped): init acc2 = b2, accumulate ----
        f32x4 acc2[8];
        #pragma unroll
        for (int nt = 0; nt < 8; ++nt)
            acc2[nt] = *(const f32x4*)&sB2[nt * 16 + g * 4];
        #pragma unroll
        for (int ks2 = 0; ks2 < 4; ++ks2) {
            #pragma unroll
            for (int nt = 0; nt < 8; ++nt) {
                bf16x8 w = *(const bf16x8*)&sW2[(nt * 16 + r) * W2S + ks2 * 32 + g * 8];
                acc2[nt] = __builtin_amdgcn_mfma_f32_16x16x32_bf16(w, hb[ks2], acc2[nt], 0, 0, 0);
            }
        }

        // ---- relu + f32x4 store: lane (r,g) -> out[e][nt*16 + g*4 .. +4) ----
        float* ob = out + (size_t)e * EDGEMB;
        #pragma unroll
        for (int nt = 0; nt < 8; ++nt) {
            f32x4 v = acc2[nt];
            v[0] = v[0] > 0.f ? v[0] : 0.f;
            v[1] = v[1] > 0.f ? v[1] : 0.f;
            v[2] = v[2] > 0.f ? v[2] : 0.f;
            v[3] = v[3] > 0.f ? v[3] : 0.f;
            *(f32x4*)&ob[nt * 16 + g * 4] = v;
        }
    }
}

extern "C" void kernel_launch(void* const* d_in, const int* in_sizes, int n_in,
                              void* d_out, int out_size, void* d_ws, size_t ws_size,
                              hipStream_t stream) {
    const float* node_features = (const float*)d_in[0];
    const float* node_hidden   = (const float*)d_in[1];
    const float* distance      = (const float*)d_in[2];
    const int*   src_idx       = (const int*)d_in[3];
    const int*   dst_idx       = (const int*)d_in[4];
    const float* W1 = (const float*)d_in[5];
    const float* b1 = (const float*)d_in[6];
    const float* W2 = (const float*)d_in[7];
    const float* b2 = (const float*)d_in[8];
    float* out = (float*)d_out;

    const int prepThreads = W1_ELEMS + W2_ELEMS;
    prep_weights<<<(prepThreads + 255) / 256, 256, 0, stream>>>(W1, b1, W2);

    constexpr int PREP_MAX = NNODES * NODEMB / 8;  // 800000 >= NEDGES, NNODES
    prep_nodes<<<(PREP_MAX + 255) / 256, 256, 0, stream>>>(
        node_hidden, node_features, distance);

    edge_mlp<<<256, 1024, 0, stream>>>(src_idx, dst_idx, b2, out);
}

// Round 6
// 878.964 us; speedup vs baseline: 1.9877x; 1.9877x over previous
//
#include <hip/hip_runtime.h>
#include <hip/hip_bf16.h>

typedef __bf16 bf16_t;
typedef __bf16 bf16x8 __attribute__((ext_vector_type(8)));
typedef __bf16 bf16x4 __attribute__((ext_vector_type(4)));
typedef float f32x4 __attribute__((ext_vector_type(4)));

constexpr int D = 128;            // NODEMB == HIDDEN == EDGEMB
constexpr int NEDGES = 800000;
constexpr int NNODES = 50000;

constexpr int WUS = 168;          // K-stride for w1dt/w1st: 160 used (5x32), +8 pad
constexpr int W2S = 136;          // K-stride for W2T: 128 used, +8 pad
constexpr int WU_ELEMS = D * WUS; // 21504
constexpr int W2_ELEMS = D * W2S; // 17408
constexpr int TILE_EDGES = 128;   // 8 waves x 16 edges
constexpr int NTILES = NEDGES / TILE_EDGES;   // 6250
constexpr int NODE_TILES = NNODES / 16;       // 3125

// ---------------------------------------------------------------------------
// Module-global tables (allocated at .so load — graph-capture safe; rebuilt
// from restored inputs every launch).
// ---------------------------------------------------------------------------
__device__ __align__(16) bf16_t g_w1dt[WU_ELEMS];  // [j][k] dst-half of W1 (+b1 row)
__device__ __align__(16) bf16_t g_w1st[WU_ELEMS];  // [j][k] src-half of W1
__device__ __align__(16) bf16_t g_w2t[W2_ELEMS];   // [n][k]
__device__ __align__(16) bf16_t g_wd[D];           // W1 distance row
__device__ __align__(16) bf16_t g_u[(size_t)NNODES * D];  // u[n] = W1d^T x_n + b1
__device__ __align__(16) bf16_t g_v[(size_t)NNODES * D];  // v[n] = W1s^T x_n

__device__ __forceinline__ bf16x8 cvt8(f32x4 lo, f32x4 hi) {
    bf16x8 t;
    t[0] = (bf16_t)lo[0]; t[1] = (bf16_t)lo[1]; t[2] = (bf16_t)lo[2]; t[3] = (bf16_t)lo[3];
    t[4] = (bf16_t)hi[0]; t[5] = (bf16_t)hi[1]; t[6] = (bf16_t)hi[2]; t[7] = (bf16_t)hi[3];
    return t;
}

// ---------------------------------------------------------------------------
// Prep 1: weight tables.
// w1dt[j][k]: k<128 -> W1[2+k][j] (dst_hidden), k=128/129 -> W1[0/1][j]
//             (dst_feat), k=130 -> b1[j] (x=1 row), else 0.
// w1st[j][k]: k<128 -> W1[132+k][j] (src_hidden), k=128/129 -> W1[130/131][j]
//             (src_feat), else 0.
// w2t[n][k]:  k<128 -> W2[k][n], else 0.   wd[j] = W1[260][j].
// ---------------------------------------------------------------------------
__global__ void prep_w(const float* __restrict__ W1, const float* __restrict__ b1,
                       const float* __restrict__ W2) {
    int i = blockIdx.x * blockDim.x + threadIdx.x;
    if (i < WU_ELEMS) {
        int j = i / WUS, k = i - j * WUS;
        float v = 0.f;
        if (k < 128)       v = W1[(2 + k) * D + j];
        else if (k == 128) v = W1[0 * D + j];
        else if (k == 129) v = W1[1 * D + j];
        else if (k == 130) v = b1[j];
        g_w1dt[j * WUS + k] = (bf16_t)v;
    } else if (i < 2 * WU_ELEMS) {
        int t = i - WU_ELEMS;
        int j = t / WUS, k = t - j * WUS;
        float v = 0.f;
        if (k < 128)       v = W1[(132 + k) * D + j];
        else if (k == 128) v = W1[130 * D + j];
        else if (k == 129) v = W1[131 * D + j];
        g_w1st[j * WUS + k] = (bf16_t)v;
    } else if (i < 2 * WU_ELEMS + W2_ELEMS) {
        int t = i - 2 * WU_ELEMS;
        int n = t / W2S, k = t - n * W2S;
        float v = (k < 128) ? W2[k * D + n] : 0.f;
        g_w2t[n * W2S + k] = (bf16_t)v;
    } else if (i < 2 * WU_ELEMS + W2_ELEMS + D) {
        int j = i - (2 * WU_ELEMS + W2_ELEMS);
        g_wd[j] = (bf16_t)W1[260 * D + j];
    }
}

// ---------------------------------------------------------------------------
// Prep 2: per-node u/v via MFMA (dense, coalesced: node rows sequential).
// Swapped operands: lane (r,g) ends with u[node r][nt*16 + g*4 + i].
// ---------------------------------------------------------------------------
__global__ __launch_bounds__(512, 4) void prep_uv(const float* __restrict__ nh,
                                                  const float* __restrict__ nf) {
    __shared__ bf16_t sWd[WU_ELEMS];  // 43,008 B
    __shared__ bf16_t sWs[WU_ELEMS];  // 43,008 B

    const int tid = threadIdx.x;
    {
        const uint4* gd = (const uint4*)g_w1dt;
        const uint4* gs = (const uint4*)g_w1st;
        uint4* ld = (uint4*)sWd;
        uint4* ls = (uint4*)sWs;
        for (int i = tid; i < WU_ELEMS / 8; i += 512) { ld[i] = gd[i]; ls[i] = gs[i]; }
    }
    __syncthreads();

    const int wid  = tid >> 6;
    const int lane = tid & 63;
    const int r    = lane & 15;
    const int g    = lane >> 4;

    for (int t = blockIdx.x * 8 + wid; t < NODE_TILES; t += (int)gridDim.x * 8) {
        const int n = t * 16 + r;
        const f32x4* xp = (const f32x4*)(nh + (size_t)n * D);

        bf16x8 a[5];
        #pragma unroll
        for (int ks = 0; ks < 4; ++ks)
            a[ks] = cvt8(xp[ks * 8 + g * 2], xp[ks * 8 + g * 2 + 1]);
        {
            bf16x8 tt;
            #pragma unroll
            for (int j = 0; j < 8; ++j) tt[j] = (bf16_t)0.f;
            if (g == 0) {           // k=128,129 feat; k=130 the "1" for b1 row
                tt[0] = (bf16_t)nf[2 * n];
                tt[1] = (bf16_t)nf[2 * n + 1];
                tt[2] = (bf16_t)1.f;
            }
            a[4] = tt;
        }

        f32x4 au[8], av[8];
        #pragma unroll
        for (int nt = 0; nt < 8; ++nt) {
            au[nt][0]=0.f; au[nt][1]=0.f; au[nt][2]=0.f; au[nt][3]=0.f;
            av[nt][0]=0.f; av[nt][1]=0.f; av[nt][2]=0.f; av[nt][3]=0.f;
        }
        #pragma unroll
        for (int ks = 0; ks < 5; ++ks) {
            #pragma unroll
            for (int nt = 0; nt < 8; ++nt) {
                bf16x8 wd_ = *(const bf16x8*)&sWd[(nt * 16 + r) * WUS + ks * 32 + g * 8];
                au[nt] = __builtin_amdgcn_mfma_f32_16x16x32_bf16(wd_, a[ks], au[nt], 0, 0, 0);
                bf16x8 ws_ = *(const bf16x8*)&sWs[(nt * 16 + r) * WUS + ks * 32 + g * 8];
                av[nt] = __builtin_amdgcn_mfma_f32_16x16x32_bf16(ws_, a[ks], av[nt], 0, 0, 0);
            }
        }

        bf16_t* up = g_u + (size_t)n * D;
        bf16_t* vp = g_v + (size_t)n * D;
        #pragma unroll
        for (int nt = 0; nt < 8; ++nt) {
            bf16x4 pu, pv;
            #pragma unroll
            for (int i = 0; i < 4; ++i) { pu[i] = (bf16_t)au[nt][i]; pv[i] = (bf16_t)av[nt][i]; }
            *(bf16x4*)&up[nt * 16 + g * 4] = pu;
            *(bf16x4*)&vp[nt * 16 + g * 4] = pv;
        }
    }
}

// ---------------------------------------------------------------------------
// Main edge kernel: h = relu(u[dst] + v[src] + dist*wd) built directly in
// layer-2 fragment layout (gather layout == fragment layout, no transpose,
// no layer-1 MFMAs), then 32 MFMAs vs W2 from LDS, f32x4 stores.
// ---------------------------------------------------------------------------
__global__ __launch_bounds__(512, 4) void edge_mlp(
    const int* __restrict__ src_idx,
    const int* __restrict__ dst_idx,
    const float* __restrict__ distance,
    const float* __restrict__ b2,
    float* __restrict__ out)
{
    __shared__ bf16_t sW2[W2_ELEMS];   // 34,816 B
    __shared__ float  sB2[D];          //     512 B

    const int tid = threadIdx.x;
    {
        const uint4* g2 = (const uint4*)g_w2t;
        uint4* l2 = (uint4*)sW2;
        for (int i = tid; i < W2_ELEMS / 8; i += 512) l2[i] = g2[i];
        if (tid < D) sB2[tid] = b2[tid];
    }
    __syncthreads();

    const int wid  = tid >> 6;
    const int lane = tid & 63;
    const int r    = lane & 15;
    const int g    = lane >> 4;

    // distance-row fragments (lane-resident constants)
    bf16x8 wdf[4];
    #pragma unroll
    for (int ks = 0; ks < 4; ++ks)
        wdf[ks] = *(const bf16x8*)&g_wd[ks * 32 + g * 8];

    for (int tile = blockIdx.x; tile < NTILES; tile += (int)gridDim.x) {
        const int e  = tile * TILE_EDGES + wid * 16 + r;
        const int di = dst_idx[e];
        const int si = src_idx[e];
        const float dist = distance[e];

        bf16x8 uf[4], vf[4];
        const bf16x8* up = (const bf16x8*)(g_u + (size_t)di * D);
        const bf16x8* vp = (const bf16x8*)(g_v + (size_t)si * D);
        #pragma unroll
        for (int ks = 0; ks < 4; ++ks) uf[ks] = up[ks * 4 + g];
        #pragma unroll
        for (int ks = 0; ks < 4; ++ks) vf[ks] = vp[ks * 4 + g];

        // h fragment: relu(u + v + dist*wd), already in B-operand layout
        bf16x8 hb[4];
        #pragma unroll
        for (int ks = 0; ks < 4; ++ks) {
            #pragma unroll
            for (int j = 0; j < 8; ++j) {
                float h = (float)uf[ks][j] + (float)vf[ks][j] + dist * (float)wdf[ks][j];
                hb[ks][j] = (bf16_t)(h > 0.f ? h : 0.f);
            }
        }

        // layer 2 (swapped): lane (r,g) -> out[e][nt*16+g*4+i]
        f32x4 acc2[8];
        #pragma unroll
        for (int nt = 0; nt < 8; ++nt)
            acc2[nt] = *(const f32x4*)&sB2[nt * 16 + g * 4];
        #pragma unroll
        for (int ks = 0; ks < 4; ++ks) {
            #pragma unroll
            for (int nt = 0; nt < 8; ++nt) {
                bf16x8 w = *(const bf16x8*)&sW2[(nt * 16 + r) * W2S + ks * 32 + g * 8];
                acc2[nt] = __builtin_amdgcn_mfma_f32_16x16x32_bf16(w, hb[ks], acc2[nt], 0, 0, 0);
            }
        }

        float* ob = out + (size_t)e * D;
        #pragma unroll
        for (int nt = 0; nt < 8; ++nt) {
            f32x4 v = acc2[nt];
            v[0] = v[0] > 0.f ? v[0] : 0.f;
            v[1] = v[1] > 0.f ? v[1] : 0.f;
            v[2] = v[2] > 0.f ? v[2] : 0.f;
            v[3] = v[3] > 0.f ? v[3] : 0.f;
            *(f32x4*)&ob[nt * 16 + g * 4] = v;
        }
    }
}

extern "C" void kernel_launch(void* const* d_in, const int* in_sizes, int n_in,
                              void* d_out, int out_size, void* d_ws, size_t ws_size,
                              hipStream_t stream) {
    const float* node_features = (const float*)d_in[0];
    const float* node_hidden   = (const float*)d_in[1];
    const float* distance      = (const float*)d_in[2];
    const int*   src_idx       = (const int*)d_in[3];
    const int*   dst_idx       = (const int*)d_in[4];
    const float* W1 = (const float*)d_in[5];
    const float* b1 = (const float*)d_in[6];
    const float* W2 = (const float*)d_in[7];
    const float* b2 = (const float*)d_in[8];
    float* out = (float*)d_out;

    const int wThreads = 2 * WU_ELEMS + W2_ELEMS + D;  // 60544
    prep_w<<<(wThreads + 255) / 256, 256, 0, stream>>>(W1, b1, W2);

    prep_uv<<<(NODE_TILES + 7) / 8, 512, 0, stream>>>(node_hidden, node_features);

    edge_mlp<<<1024, 512, 0, stream>>>(src_idx, dst_idx, distance, b2, out);
}